// Round 1
// baseline (882.244 us; speedup 1.0000x reference)
//
#include <hip/hip_runtime.h>
#include <hip/hip_bf16.h>

// Problem dims
#define B_  2
#define C_  256
#define N_  4096
#define R_  8
#define G_  4
#define CG_ 64          // C/G

// Workspace layout (in floats):
//  q[4][B][R][N]  : p in {0:qL, 1:kU, 2:qU, 3:kL}
//  v[2][B][C][N]  : d in {0:vU (for LU), 1:vL (for UL)}
//  Zinv[2][B][N]
#define QSZ   (B_*R_*N_)          // 65536
#define VSZ   (B_*C_*N_)          // 2097152
#define OFF_V (4*QSZ)             // 262144
#define OFF_Z (OFF_V + 2*VSZ)     // 4456448
// total floats: 4472832 (~17.9 MB)

// ---------------------------------------------------------------------------
// Kernel 1: q/k projections.  y[p][b][o][n] = bias[o] + sum_c w[o][c] x[b][c][n]
// p: 0 qL<-fL, 1 kU<-fU, 2 qU<-fU, 3 kL<-fL.  grid(16, B, 4), block 256.
// ---------------------------------------------------------------------------
__global__ __launch_bounds__(256) void proj_qk(
    const float* __restrict__ fL, const float* __restrict__ fU,
    const float* __restrict__ w0, const float* __restrict__ b0,
    const float* __restrict__ w1, const float* __restrict__ b1,
    const float* __restrict__ w2, const float* __restrict__ b2,
    const float* __restrict__ w3, const float* __restrict__ b3,
    float* __restrict__ ws)
{
    const int p = blockIdx.z;
    const int b = blockIdx.y;
    const int n = blockIdx.x * 256 + threadIdx.x;

    const float* src  = (p == 0 || p == 3) ? fL : fU;
    const float* w    = (p == 0) ? w0 : (p == 1) ? w1 : (p == 2) ? w2 : w3;
    const float* bias = (p == 0) ? b0 : (p == 1) ? b1 : (p == 2) ? b2 : b3;

    __shared__ float wl[R_ * C_];
    for (int i = threadIdx.x; i < R_ * C_; i += 256) wl[i] = w[i];
    __syncthreads();

    float acc[R_];
#pragma unroll
    for (int o = 0; o < R_; o++) acc[o] = 0.f;

    const float* x = src + (size_t)b * C_ * N_ + n;
    for (int c = 0; c < C_; c++) {
        float xv = x[(size_t)c * N_];
#pragma unroll
        for (int o = 0; o < R_; o++) acc[o] += wl[o * C_ + c] * xv;
    }

    float* qout = ws + (size_t)p * QSZ + (size_t)b * R_ * N_ + n;
#pragma unroll
    for (int o = 0; o < R_; o++) qout[(size_t)o * N_] = acc[o] + bias[o];
}

// ---------------------------------------------------------------------------
// Kernel 2: grouped 1x1 conv v.  v[d][b][g*64+o][n] = bias[c] + sum_i w[g][o][i] x[b][g*64+i][n]
// d=0: vU<-fU (weights vU_w), d=1: vL<-fL.  grid(N/64, G, 2*B), block 256.
// Each thread: one n, 16 output channels (o4*16..o4*16+15).
// ---------------------------------------------------------------------------
__global__ __launch_bounds__(256) void gconv_v(
    const float* __restrict__ fL, const float* __restrict__ fU,
    const float* __restrict__ wU, const float* __restrict__ bU,
    const float* __restrict__ wL, const float* __restrict__ bL,
    float* __restrict__ ws)
{
    const int g = blockIdx.y;
    const int d = blockIdx.z >> 1;
    const int b = blockIdx.z & 1;
    const float* src  = (d == 0) ? fU : fL;
    const float* w    = (d == 0) ? wU : wL;   // [G][64][64]
    const float* bias = (d == 0) ? bU : bL;   // [C]

    const int n  = blockIdx.x * 64 + (threadIdx.x & 63);
    const int o4 = threadIdx.x >> 6;          // 0..3

    __shared__ float wl[CG_ * CG_];
    for (int i = threadIdx.x; i < CG_ * CG_; i += 256) wl[i] = w[g * CG_ * CG_ + i];
    __syncthreads();

    float acc[16];
#pragma unroll
    for (int j = 0; j < 16; j++) acc[j] = 0.f;

    const float* x = src + (size_t)b * C_ * N_ + (size_t)g * CG_ * N_ + n;
    for (int i = 0; i < CG_; i++) {
        float xv = x[(size_t)i * N_];
#pragma unroll
        for (int j = 0; j < 16; j++) acc[j] += wl[(o4 * 16 + j) * CG_ + i] * xv;
    }

    float* vout = ws + OFF_V + (size_t)d * VSZ + (size_t)b * C_ * N_
                + (size_t)g * CG_ * N_ + n;
#pragma unroll
    for (int j = 0; j < 16; j++) {
        int oc = o4 * 16 + j;
        vout[(size_t)oc * N_] = acc[j] + bias[g * CG_ + oc];
    }
}

// ---------------------------------------------------------------------------
// Kernel 3: Zinv[d][b][n] = 1 / sum_m exp( sum_r q[r][n] k[r][m] )
// No max-subtraction: |s| <~ 25 with these 0.05-scaled weights, safe in fp32.
// grid(N/64, B, 2), block 256. Thread: (n_local = tid>>2, m-group = tid&3 covers 1024 m).
// ---------------------------------------------------------------------------
__global__ __launch_bounds__(256) void softmax_z(float* __restrict__ ws)
{
    const int d  = blockIdx.z;
    const int b  = blockIdx.y;
    const int nl = threadIdx.x >> 2;
    const int mg = threadIdx.x & 3;
    const int n  = blockIdx.x * 64 + nl;

    const float* q = ws + (size_t)((d == 0) ? 0 : 2) * QSZ + (size_t)b * R_ * N_;
    const float* k = ws + (size_t)((d == 0) ? 1 : 3) * QSZ + (size_t)b * R_ * N_;

    float qv[R_];
#pragma unroll
    for (int r = 0; r < R_; r++) qv[r] = q[(size_t)r * N_ + n];

    float Z = 0.f;
    const int m0 = mg * 1024;
    for (int m = m0; m < m0 + 1024; m += 4) {
        float s0 = 0.f, s1 = 0.f, s2 = 0.f, s3 = 0.f;
#pragma unroll
        for (int r = 0; r < R_; r++) {
            const float4 kv = *reinterpret_cast<const float4*>(&k[(size_t)r * N_ + m]);
            s0 += qv[r] * kv.x; s1 += qv[r] * kv.y;
            s2 += qv[r] * kv.z; s3 += qv[r] * kv.w;
        }
        Z += __expf(s0) + __expf(s1) + __expf(s2) + __expf(s3);
    }
    // reduce over the 4 m-groups (adjacent lanes)
    Z += __shfl_xor(Z, 1);
    Z += __shfl_xor(Z, 2);
    if (mg == 0)
        ws[OFF_Z + (size_t)d * (B_ * N_) + (size_t)b * N_ + n] = 1.0f / Z;
}

// ---------------------------------------------------------------------------
// Kernel 4: out[d][b][c][m] = f[c][m] + beta * sum_n v'[c][n] * exp(s[n][m])
// v'[c][n] = v[c][n] * Zinv[n].  E-tile regenerated on the fly from rank-8 q/k.
// Tiles: BM=128 (c) x BN=64 (m) x BK=32 (n). 256 threads, 8x4 micro-tile.
// grid(N/BN=64, C/BM=2, 2*B=4) = 512 blocks -> 2 blocks/CU.
// ---------------------------------------------------------------------------
#define BM 128
#define BN 64
#define BK 32
#define VS_STRIDE (BM + 4)   // 132: breaks the 32-way write conflict, keeps 16B-aligned rows

__global__ __launch_bounds__(256, 2) void attn_gemm(
    const float* __restrict__ fL, const float* __restrict__ fU,
    const float* __restrict__ betap, const float* __restrict__ ws,
    float* __restrict__ out)
{
    const int d  = blockIdx.z >> 1;
    const int b  = blockIdx.z & 1;
    const int m0 = blockIdx.x * BN;
    const int c0 = blockIdx.y * BM;

    const float* q    = ws + (size_t)((d == 0) ? 0 : 2) * QSZ + (size_t)b * R_ * N_;
    const float* k    = ws + (size_t)((d == 0) ? 1 : 3) * QSZ + (size_t)b * R_ * N_;
    const float* v    = ws + OFF_V + (size_t)d * VSZ + (size_t)b * C_ * N_;
    const float* zinv = ws + OFF_Z + (size_t)d * (B_ * N_) + (size_t)b * N_;
    const float* f    = ((d == 0) ? fL : fU) + (size_t)b * C_ * N_;
    float*       o    = out + (size_t)d * VSZ + (size_t)b * C_ * N_;
    const float  beta = *betap;

    __shared__ float ks[R_][BN];
    __shared__ float Vs[BK][VS_STRIDE];
    __shared__ float Es[BK][BN];

    const int tid = threadIdx.x;

    // Stage the k-strip for this m-tile once (fixed across the whole K-loop).
    for (int i = tid; i < R_ * BN; i += 256)
        ks[i / BN][i % BN] = k[(size_t)(i / BN) * N_ + m0 + (i % BN)];

    float acc[8][4];
#pragma unroll
    for (int i = 0; i < 8; i++)
#pragma unroll
        for (int j = 0; j < 4; j++) acc[i][j] = 0.f;

    const int tx = tid & 15;        // m: 4 cols each
    const int ty = tid >> 4;        // c: 8 rows each
    const int vj = tid & 31;        // n within BK for V staging
    const int vc = tid >> 5;        // 0..7
    const int ejn = tid >> 3;       // 0..31  (n row of E)
    const int ejm = (tid & 7) * 8;  // 8 consecutive m cols of E

    __syncthreads();   // ks ready

    for (int n0 = 0; n0 < N_; n0 += BK) {
        // Phase 1a: stage V' tile (transposed: Vs[n][c]), scaled by Zinv.
        const float zv = zinv[n0 + vj];
#pragma unroll
        for (int p = 0; p < 16; p++)
            Vs[vj][vc + 8 * p] = v[(size_t)(c0 + vc + 8 * p) * N_ + n0 + vj] * zv;

        // Phase 1b: regenerate E tile = exp(q^T k) from rank-8 data.
        {
            float s[8];
#pragma unroll
            for (int p = 0; p < 8; p++) s[p] = 0.f;
#pragma unroll
            for (int r = 0; r < R_; r++) {
                const float qv = q[(size_t)r * N_ + n0 + ejn];  // broadcast within 8 lanes
#pragma unroll
                for (int p = 0; p < 8; p++) s[p] += qv * ks[r][ejm + p];
            }
#pragma unroll
            for (int p = 0; p < 8; p++) Es[ejn][ejm + p] = __expf(s[p]);
        }
        __syncthreads();

        // Phase 2: 128x64 += 128x32 * 32x64 rank-1 updates.
#pragma unroll
        for (int kk = 0; kk < BK; kk++) {
            float va[8], eb[4];
            *reinterpret_cast<float4*>(&va[0]) = *reinterpret_cast<const float4*>(&Vs[kk][ty * 8]);
            *reinterpret_cast<float4*>(&va[4]) = *reinterpret_cast<const float4*>(&Vs[kk][ty * 8 + 4]);
            *reinterpret_cast<float4*>(&eb[0]) = *reinterpret_cast<const float4*>(&Es[kk][tx * 4]);
#pragma unroll
            for (int i = 0; i < 8; i++)
#pragma unroll
                for (int j = 0; j < 4; j++) acc[i][j] += va[i] * eb[j];
        }
        __syncthreads();
    }

    // Epilogue: out = f + beta * acc  (float4 over m)
#pragma unroll
    for (int i = 0; i < 8; i++) {
        const int c = c0 + ty * 8 + i;
        const size_t off = (size_t)c * N_ + m0 + tx * 4;
        const float4 fv = *reinterpret_cast<const float4*>(&f[off]);
        float4 ov;
        ov.x = fv.x + beta * acc[i][0];
        ov.y = fv.y + beta * acc[i][1];
        ov.z = fv.z + beta * acc[i][2];
        ov.w = fv.w + beta * acc[i][3];
        *reinterpret_cast<float4*>(&o[off]) = ov;
    }
}

// ---------------------------------------------------------------------------
extern "C" void kernel_launch(void* const* d_in, const int* in_sizes, int n_in,
                              void* d_out, int out_size, void* d_ws, size_t ws_size,
                              hipStream_t stream)
{
    const float* fL   = (const float*)d_in[0];
    const float* fU   = (const float*)d_in[1];
    const float* qL_w = (const float*)d_in[2];
    const float* qL_b = (const float*)d_in[3];
    const float* kU_w = (const float*)d_in[4];
    const float* kU_b = (const float*)d_in[5];
    const float* vU_w = (const float*)d_in[6];
    const float* vU_b = (const float*)d_in[7];
    const float* qU_w = (const float*)d_in[8];
    const float* qU_b = (const float*)d_in[9];
    const float* kL_w = (const float*)d_in[10];
    const float* kL_b = (const float*)d_in[11];
    const float* vL_w = (const float*)d_in[12];
    const float* vL_b = (const float*)d_in[13];
    const float* beta = (const float*)d_in[14];

    float* wsf  = (float*)d_ws;
    float* outf = (float*)d_out;

    proj_qk<<<dim3(N_ / 256, B_, 4), 256, 0, stream>>>(
        fL, fU, qL_w, qL_b, kU_w, kU_b, qU_w, qU_b, kL_w, kL_b, wsf);

    gconv_v<<<dim3(N_ / 64, G_, 2 * B_), 256, 0, stream>>>(
        fL, fU, vU_w, vU_b, vL_w, vL_b, wsf);

    softmax_z<<<dim3(N_ / 64, B_, 2), 256, 0, stream>>>(wsf);

    attn_gemm<<<dim3(N_ / BN, C_ / BM, 2 * B_), 256, 0, stream>>>(
        fL, fU, beta, wsf, outf);
}

// Round 2
// 270.862 us; speedup vs baseline: 3.2572x; 3.2572x over previous
//
#include <hip/hip_runtime.h>
#include <hip/hip_bf16.h>

// Problem dims
#define B_  2
#define C_  256
#define N_  4096
#define R_  8
#define G_  4
#define CG_ 64

typedef __attribute__((ext_vector_type(8))) short short8;
typedef __attribute__((ext_vector_type(4))) float f32x4;

#define MFMA16(a, b, c) __builtin_amdgcn_mfma_f32_16x16x32_bf16((a), (b), (c), 0, 0, 0)
#define EXP2F(x) __builtin_amdgcn_exp2f(x)
#define LOG2E 1.44269504088896f

// -------- bf16 helpers (round-to-nearest-even) --------
__device__ inline unsigned short f2bf(float f) {
    union { float f; unsigned int u; } v; v.f = f;
    unsigned int r = (v.u + 0x7FFFu + ((v.u >> 16) & 1u)) >> 16;
    return (unsigned short)r;
}
__device__ inline float bf2f(unsigned short h) {
    union { unsigned int u; float f; } v; v.u = ((unsigned int)h) << 16;
    return v.f;
}

// Workspace layout:
//  qT  bf16 [d][b][n][8]   (log2e folded)    : ushort idx 0,      els 131072
//  kT  bf16 [d][b][m][8]                     : ushort idx 131072, els 131072
//  Zinv f32 [d][b][n]                        : byte off 512K -> float idx 131072
//  Vz  bf16 [d][b][c][n]  (= v * Zinv[n])    : byte off 576K -> ushort idx 294912
#define QT_OFF  0
#define KT_OFF  131072
#define ZI_OFFF 131072          // in floats
#define VZ_OFF  294912          // in ushorts
// total ~8.95 MB (<17.9 MB known-safe)

// ---------------------------------------------------------------------------
// Kernel 1: projections -> transposed bf16 strips.
// src s=0: fL -> qT[d=0] (qL, *log2e) and kT[d=1] (kL)
// src s=1: fU -> qT[d=1] (qU, *log2e) and kT[d=0] (kU)
// grid(64, B, 2), block 256.
// ---------------------------------------------------------------------------
__global__ __launch_bounds__(256) void proj_qk(
    const float* __restrict__ fL, const float* __restrict__ fU,
    const float* __restrict__ qLw, const float* __restrict__ qLb,
    const float* __restrict__ kUw, const float* __restrict__ kUb,
    const float* __restrict__ qUw, const float* __restrict__ qUb,
    const float* __restrict__ kLw, const float* __restrict__ kLb,
    unsigned short* __restrict__ wsu)
{
    const int s = blockIdx.z;
    const int b = blockIdx.y;
    const int t = threadIdx.x;

    const float* src = s ? fU : fL;
    const float* wq  = s ? qUw : qLw;
    const float* bq  = s ? qUb : qLb;
    const float* wk  = s ? kUw : kLw;   // s=0 -> kL, s=1 -> kU
    const float* bk  = s ? kUb : kLb;
    const int dq = s;        // qT dir
    const int dk = 1 - s;    // kT dir

    __shared__ float wl[16 * C_];       // rows 0-7: wq, 8-15: wk
    __shared__ float red[4][64][16];

    for (int i = t; i < 8 * C_; i += 256) wl[i] = wq[i];
    for (int i = t; i < 8 * C_; i += 256) wl[8 * C_ + i] = wk[i];
    __syncthreads();

    const int nl = t & 63;
    const int cs = t >> 6;              // c-slice 0..3
    const int n  = blockIdx.x * 64 + nl;

    float acc[16];
#pragma unroll
    for (int o = 0; o < 16; o++) acc[o] = 0.f;

    const float* x = src + (size_t)b * C_ * N_ + n;
    for (int c = cs * 64; c < cs * 64 + 64; c++) {
        float xv = x[(size_t)c * N_];
#pragma unroll
        for (int o = 0; o < 16; o++) acc[o] += wl[o * C_ + c] * xv;
    }
#pragma unroll
    for (int o = 0; o < 16; o++) red[cs][nl][o] = acc[o];
    __syncthreads();

    // thread t: n-local = t&63, o-group = (t>>6)*4
    const int og = (t >> 6) * 4;
    unsigned short pk[4];
#pragma unroll
    for (int j = 0; j < 4; j++) {
        const int o = og + j;
        float v = red[0][nl][o] + red[1][nl][o] + red[2][nl][o] + red[3][nl][o];
        if (o < 8) v = (v + bq[o]) * LOG2E;
        else       v = v + bk[o - 8];
        pk[j] = f2bf(v);
    }
    const int nn = blockIdx.x * 64 + nl;
    unsigned short* dst;
    if (og < 8) dst = wsu + QT_OFF + ((size_t)(dq * B_ + b) * N_ + nn) * 8 + og;
    else        dst = wsu + KT_OFF + ((size_t)(dk * B_ + b) * N_ + nn) * 8 + (og - 8);
    *reinterpret_cast<ushort4*>(dst) = *reinterpret_cast<ushort4*>(pk);
}

// ---------------------------------------------------------------------------
// Kernel 2: Zinv[d][b][n] = 1 / sum_m exp2(s'[n][m]) via zero-padded rank-8 MFMA.
// grid(N/64, B, 2), block 256 (4 waves; wave w owns n-rows w*16..w*16+15).
// ---------------------------------------------------------------------------
__global__ __launch_bounds__(256) void zcalc(unsigned short* __restrict__ wsu,
                                             float* __restrict__ wsf)
{
    const int d = blockIdx.z;
    const int b = blockIdx.y;
    const int t = threadIdx.x;
    const int w = t >> 6;
    const int l = t & 63;
    const int n0 = blockIdx.x * 64;

    const unsigned short* qT = wsu + QT_OFF + (size_t)(d * B_ + b) * N_ * 8;
    const unsigned short* kT = wsu + KT_OFF + (size_t)(d * B_ + b) * N_ * 8;

    __shared__ unsigned short qf[64 * 8];
    if (t < 64)
        *reinterpret_cast<uint4*>(qf + t * 8) =
            *reinterpret_cast<const uint4*>(qT + (size_t)(n0 + t) * 8);
    __syncthreads();

    // A-frag: row n-local = w*16 + (l&15); k-chunk content duplicated for l>=16 (annihilated by B=0)
    const short8 afrag = *reinterpret_cast<const short8*>(qf + (w * 16 + (l & 15)) * 8);

    float zacc[4] = {0.f, 0.f, 0.f, 0.f};
    const f32x4 zero = {0.f, 0.f, 0.f, 0.f};

    for (int mt = 0; mt < 64; mt++) {
        short8 bk[4];
#pragma unroll
        for (int kb = 0; kb < 4; kb++) {
            if (l < 16)
                bk[kb] = *reinterpret_cast<const short8*>(
                    kT + (size_t)(mt * 64 + kb * 16 + l) * 8);
            else
                bk[kb] = short8{0, 0, 0, 0, 0, 0, 0, 0};
        }
#pragma unroll
        for (int kb = 0; kb < 4; kb++) {
            f32x4 sv = MFMA16(afrag, bk[kb], zero);
#pragma unroll
            for (int r = 0; r < 4; r++) zacc[r] += EXP2F(sv[r]);
        }
    }

    // reduce over the 16 column-lanes (low 4 bits of lane id)
#pragma unroll
    for (int r = 0; r < 4; r++) {
        float v = zacc[r];
        v += __shfl_xor(v, 1);
        v += __shfl_xor(v, 2);
        v += __shfl_xor(v, 4);
        v += __shfl_xor(v, 8);
        if ((l & 15) == 0) {
            const int n = n0 + w * 16 + (l >> 4) * 4 + r;
            wsf[ZI_OFFF + (size_t)(d * B_ + b) * N_ + n] = 1.0f / v;
        }
    }
}

// ---------------------------------------------------------------------------
// Kernel 3: grouped conv -> Vz bf16 with Zinv folded.
// d=0: src fU, weights vU;  d=1: src fL, weights vL.
// grid(N/64, G, 2*B) z=d*2+b, block 256.
// ---------------------------------------------------------------------------
__global__ __launch_bounds__(256) void gconv_v(
    const float* __restrict__ fL, const float* __restrict__ fU,
    const float* __restrict__ wU, const float* __restrict__ bU,
    const float* __restrict__ wL, const float* __restrict__ bL,
    unsigned short* __restrict__ wsu, const float* __restrict__ wsf)
{
    const int g = blockIdx.y;
    const int d = blockIdx.z >> 1;
    const int b = blockIdx.z & 1;
    const float* src  = (d == 0) ? fU : fL;
    const float* wgt  = (d == 0) ? wU : wL;
    const float* bias = (d == 0) ? bU : bL;

    const int n  = blockIdx.x * 64 + (threadIdx.x & 63);
    const int o4 = threadIdx.x >> 6;

    __shared__ float wl[CG_ * CG_];
    for (int i = threadIdx.x; i < CG_ * CG_; i += 256) wl[i] = wgt[g * CG_ * CG_ + i];
    __syncthreads();

    float acc[16];
#pragma unroll
    for (int j = 0; j < 16; j++) acc[j] = 0.f;

    const float* x = src + (size_t)b * C_ * N_ + (size_t)g * CG_ * N_ + n;
    for (int i = 0; i < CG_; i++) {
        float xv = x[(size_t)i * N_];
#pragma unroll
        for (int j = 0; j < 16; j++) acc[j] += wl[(o4 * 16 + j) * CG_ + i] * xv;
    }

    const float zv = wsf[ZI_OFFF + (size_t)(d * B_ + b) * N_ + n];
    unsigned short* vout = wsu + VZ_OFF
        + ((size_t)(d * B_ + b) * C_ + (size_t)g * CG_) * N_ + n;
#pragma unroll
    for (int j = 0; j < 16; j++) {
        const int oc = o4 * 16 + j;
        vout[(size_t)oc * N_] = f2bf((acc[j] + bias[g * CG_ + oc]) * zv);
    }
}

// ---------------------------------------------------------------------------
// Kernel 4: out[c][m] = f[c][m] + beta * sum_n Vz[c][n] * exp2(s'[n][m])
// Tile: 128(c) x 64(m) x BK=64(n). grid(64, 2, 4) = 512 blocks, 256 thr.
// Per k-step: E-tile regenerated via 16 zero-padded MFMAs + exp2, then
// 64 main mfma_f32_16x16x32_bf16. k-fragments persistent in registers.
// ---------------------------------------------------------------------------
__global__ __launch_bounds__(256) void attn_gemm(
    const float* __restrict__ fL, const float* __restrict__ fU,
    const float* __restrict__ betap,
    const unsigned short* __restrict__ wsu,
    float* __restrict__ out)
{
    const int d  = blockIdx.z >> 1;
    const int b  = blockIdx.z & 1;
    const int m0 = blockIdx.x * 64;
    const int c0 = blockIdx.y * 128;
    const int t  = threadIdx.x;
    const int w  = t >> 6;
    const int l  = t & 63;

    const unsigned short* qT = wsu + QT_OFF + (size_t)(d * B_ + b) * N_ * 8;
    const unsigned short* kT = wsu + KT_OFF + (size_t)(d * B_ + b) * N_ * 8;
    const unsigned short* Vz = wsu + VZ_OFF + (size_t)(d * B_ + b) * C_ * N_;
    const float* f = ((d == 0) ? fL : fU) + (size_t)b * C_ * N_;
    float*       o = out + (size_t)(d * B_ + b) * C_ * N_;

    __shared__ unsigned short As[128 * 72];  // Vz tile [c][n], rows padded to 72
    __shared__ unsigned short Es[64 * 72];   // E tile  [m][n], rows padded to 72
    __shared__ unsigned short qf[64 * 8];    // q strip [n][8]

    // persistent k-fragments (B of the s-MFMA): real only in lanes 0..15 (k-chunk 0 = r 0..7)
    short8 kfrag[4];
#pragma unroll
    for (int kb = 0; kb < 4; kb++) {
        if (l < 16)
            kfrag[kb] = *reinterpret_cast<const short8*>(
                kT + (size_t)(m0 + kb * 16 + l) * 8);
        else
            kfrag[kb] = short8{0, 0, 0, 0, 0, 0, 0, 0};
    }

    f32x4 acc[4][2];
#pragma unroll
    for (int mb = 0; mb < 4; mb++)
#pragma unroll
        for (int nb = 0; nb < 2; nb++) acc[mb][nb] = f32x4{0.f, 0.f, 0.f, 0.f};

    const f32x4 zero = {0.f, 0.f, 0.f, 0.f};
    const int wm = w & 1;    // c-half
    const int wn = w >> 1;   // m-half
    const int cr = t >> 1;   // staging row 0..127
    const int hf = t & 1;    // staging half (32 n)

    for (int n0 = 0; n0 < N_; n0 += 64) {
        // ---- stage Vz tile + q strip ----
        const unsigned short* gA = Vz + (size_t)(c0 + cr) * N_ + n0 + hf * 32;
        uint4 a0 = *reinterpret_cast<const uint4*>(gA + 0);
        uint4 a1 = *reinterpret_cast<const uint4*>(gA + 8);
        uint4 a2 = *reinterpret_cast<const uint4*>(gA + 16);
        uint4 a3 = *reinterpret_cast<const uint4*>(gA + 24);
        unsigned short* dA = As + cr * 72 + hf * 32;
        *reinterpret_cast<uint4*>(dA + 0)  = a0;
        *reinterpret_cast<uint4*>(dA + 8)  = a1;
        *reinterpret_cast<uint4*>(dA + 16) = a2;
        *reinterpret_cast<uint4*>(dA + 24) = a3;
        if (t < 64)
            *reinterpret_cast<uint4*>(qf + t * 8) =
                *reinterpret_cast<const uint4*>(qT + (size_t)(n0 + t) * 8);
        __syncthreads();

        // ---- E-gen: s' = q^T k via padded MFMA, exp2, write Es[m][n] bf16 ----
        {
            const short8 afrag = *reinterpret_cast<const short8*>(
                qf + (w * 16 + (l & 15)) * 8);
#pragma unroll
            for (int kb = 0; kb < 4; kb++) {
                f32x4 sv = MFMA16(afrag, kfrag[kb], zero);
                unsigned short pk[4];
#pragma unroll
                for (int r = 0; r < 4; r++) pk[r] = f2bf(EXP2F(sv[r]));
                // m = kb*16 + (l&15); n-local = w*16 + (l>>4)*4 .. +3
                *reinterpret_cast<ushort4*>(
                    Es + (kb * 16 + (l & 15)) * 72 + w * 16 + (l >> 4) * 4) =
                    *reinterpret_cast<ushort4*>(pk);
            }
        }
        __syncthreads();

        // ---- main MFMA: 128x64 += 128x64 * 64x64 ----
#pragma unroll
        for (int s = 0; s < 2; s++) {
            short8 bfr[2];
#pragma unroll
            for (int nb = 0; nb < 2; nb++)
                bfr[nb] = *reinterpret_cast<const short8*>(
                    Es + (wn * 32 + nb * 16 + (l & 15)) * 72 + (s * 4 + (l >> 4)) * 8);
#pragma unroll
            for (int mb = 0; mb < 4; mb++) {
                const short8 afr = *reinterpret_cast<const short8*>(
                    As + (wm * 64 + mb * 16 + (l & 15)) * 72 + (s * 4 + (l >> 4)) * 8);
#pragma unroll
                for (int nb = 0; nb < 2; nb++)
                    acc[mb][nb] = MFMA16(afr, bfr[nb], acc[mb][nb]);
            }
        }
        __syncthreads();
    }

    // ---- epilogue: out = f + beta * acc ----
    const float beta = *betap;
#pragma unroll
    for (int mb = 0; mb < 4; mb++) {
#pragma unroll
        for (int nb = 0; nb < 2; nb++) {
            const int c = c0 + wm * 64 + mb * 16 + (l >> 4) * 4;
            const int m = m0 + wn * 32 + nb * 16 + (l & 15);
#pragma unroll
            for (int r = 0; r < 4; r++) {
                const size_t off = (size_t)(c + r) * N_ + m;
                o[off] = f[off] + beta * acc[mb][nb][r];
            }
        }
    }
}

// ---------------------------------------------------------------------------
extern "C" void kernel_launch(void* const* d_in, const int* in_sizes, int n_in,
                              void* d_out, int out_size, void* d_ws, size_t ws_size,
                              hipStream_t stream)
{
    const float* fL   = (const float*)d_in[0];
    const float* fU   = (const float*)d_in[1];
    const float* qL_w = (const float*)d_in[2];
    const float* qL_b = (const float*)d_in[3];
    const float* kU_w = (const float*)d_in[4];
    const float* kU_b = (const float*)d_in[5];
    const float* vU_w = (const float*)d_in[6];
    const float* vU_b = (const float*)d_in[7];
    const float* qU_w = (const float*)d_in[8];
    const float* qU_b = (const float*)d_in[9];
    const float* kL_w = (const float*)d_in[10];
    const float* kL_b = (const float*)d_in[11];
    const float* vL_w = (const float*)d_in[12];
    const float* vL_b = (const float*)d_in[13];
    const float* beta = (const float*)d_in[14];

    unsigned short* wsu = (unsigned short*)d_ws;
    float*          wsf = (float*)d_ws;
    float*          outf = (float*)d_out;

    proj_qk<<<dim3(64, B_, 2), 256, 0, stream>>>(
        fL, fU, qL_w, qL_b, kU_w, kU_b, qU_w, qU_b, kL_w, kL_b, wsu);

    zcalc<<<dim3(64, B_, 2), 256, 0, stream>>>(wsu, wsf);

    gconv_v<<<dim3(64, G_, 2 * B_), 256, 0, stream>>>(
        fL, fU, vU_w, vU_b, vL_w, vL_b, wsu, wsf);

    attn_gemm<<<dim3(64, 2, 2 * B_), 256, 0, stream>>>(
        fL, fU, beta, wsu, outf);
}